// Round 1
// baseline (773.562 us; speedup 1.0000x reference)
//
#include <hip/hip_runtime.h>

#define DFEAT 64
#define NEDGES 1600000

typedef __bf16 bf16x8 __attribute__((ext_vector_type(8)));
typedef float f32x4 __attribute__((ext_vector_type(4)));

__device__ __forceinline__ __bf16 f2bf(float f) {
  unsigned u = __builtin_bit_cast(unsigned, f);
  u += 0x7FFFu + ((u >> 16) & 1u);            // RNE round to bf16
  unsigned short s = (unsigned short)(u >> 16);
  return __builtin_bit_cast(__bf16, s);
}

// out = nodes (d_out is poisoned before every timed call)
__global__ void init_out(const float* __restrict__ nodes, float* __restrict__ out) {
  int i = blockIdx.x * blockDim.x + threadIdx.x;   // 1,600,000 float4s
  ((float4*)out)[i] = ((const float4*)nodes)[i];
}

// Per wave: 16-edge tiles. Stage1: hidden = relu(X@W1 +b1) (both directions via
// k^64 trick on B side). Stage2: M = hidden@W2 + b2, atomic scatter to out.
__launch_bounds__(256, 2)
__global__ void edge_mlp(const float* __restrict__ nodes,
                         const int* __restrict__ edges,
                         const float* __restrict__ W1,
                         const float* __restrict__ b1,
                         const float* __restrict__ W2,
                         const float* __restrict__ b2,
                         float* __restrict__ out) {
  // bf16 LDS, [n][k] with 16B-block xor swizzle (blk ^ (n&15)) -> conflict-free b128
  __shared__ __bf16 w1t[128 * 128];   // 32 KB
  __shared__ __bf16 w2t[64 * 128];    // 16 KB
  __shared__ __bf16 hid[4][16 * 128]; // 16 KB (per-wave hidden tile)

  const int tid = threadIdx.x;

  // ---- stage W1 (global [k=128][n=128] f32) -> w1t bf16 [n][k] swizzled ----
  for (int it = 0; it < 16; ++it) {
    int q = it * 256 + tid;          // float4 id, 4096 total
    int k = q >> 5;                  // row (k), 32 float4 per row
    int nc = (q & 31) << 2;          // col base
    float4 v = ((const float4*)W1)[q];
    float vv[4] = {v.x, v.y, v.z, v.w};
#pragma unroll
    for (int c = 0; c < 4; ++c) {
      int n = nc + c;
      int blk = (k >> 3) ^ (n & 15);
      w1t[n * 128 + blk * 8 + (k & 7)] = f2bf(vv[c]);
    }
  }
  // ---- stage W2 (global [k=128][n=64] f32) -> w2t bf16 [n][k] swizzled ----
  for (int it = 0; it < 8; ++it) {
    int q = it * 256 + tid;          // 2048 float4
    int k = q >> 4;                  // 16 float4 per row
    int nc = (q & 15) << 2;
    float4 v = ((const float4*)W2)[q];
    float vv[4] = {v.x, v.y, v.z, v.w};
#pragma unroll
    for (int c = 0; c < 4; ++c) {
      int n = nc + c;
      int blk = (k >> 3) ^ (n & 15);
      w2t[n * 128 + blk * 8 + (k & 7)] = f2bf(vv[c]);
    }
  }
  __syncthreads();

  const int lane = tid & 63;
  const int wave = tid >> 6;
  const int col = lane & 15;        // MFMA col / A-row m
  const int quad = lane >> 4;       // MFMA quad
  __bf16* myhid = hid[wave];

  // biases held in VGPRs (b1v[nt] applies to all 4 acc rows: col-indexed)
  float b1v[8], b2v[4];
#pragma unroll
  for (int nt = 0; nt < 8; ++nt) b1v[nt] = b1[nt * 16 + col];
#pragma unroll
  for (int nt = 0; nt < 4; ++nt) b2v[nt] = b2[nt * 16 + col];

  for (int t = 0; t < 8; ++t) {
    const int e0 = blockIdx.x * 512 + wave * 128 + t * 16;
    const int e = e0 + col;         // this lane's edge (for A-frags, m = col)
    const int ie = edges[2 * e];
    const int je = edges[2 * e + 1];

    // A-fragments of X = concat(h_i, h_j): direct from global, bf16 convert.
    // lane reads X[m=col][k], k = kt*32 + quad*8 + j  (8 contiguous floats)
    bf16x8 af[4];
#pragma unroll
    for (int kt = 0; kt < 4; ++kt) {
      int k = kt * 32 + quad * 8;
      const float* src = (k < 64) ? (nodes + (long)ie * 64 + k)
                                  : (nodes + (long)je * 64 + (k - 64));
      float4 v0 = ((const float4*)src)[0];
      float4 v1 = ((const float4*)src)[1];
      bf16x8 a;
      a[0] = f2bf(v0.x); a[1] = f2bf(v0.y); a[2] = f2bf(v0.z); a[3] = f2bf(v0.w);
      a[4] = f2bf(v1.x); a[5] = f2bf(v1.y); a[6] = f2bf(v1.z); a[7] = f2bf(v1.w);
      af[kt] = a;
    }

#pragma unroll
    for (int dir = 0; dir < 2; ++dir) {
      // ---- stage 1: hidden(dir) = relu(X @ W1(dir) + b1) ----
      f32x4 acc[8];
#pragma unroll
      for (int nt = 0; nt < 8; ++nt) acc[nt] = (f32x4)0.0f;
#pragma unroll
      for (int kt = 0; kt < 4; ++kt) {
        int kblk = kt * 4 + quad;
        if (dir) kblk ^= 8;          // W1s[k] = W1[k^64]  (swapped halves)
#pragma unroll
        for (int nt = 0; nt < 8; ++nt) {
          int n = nt * 16 + col;
          const bf16x8 bf = *(const bf16x8*)&w1t[n * 128 + ((kblk ^ (n & 15)) << 3)];
          acc[nt] = __builtin_amdgcn_mfma_f32_16x16x32_bf16(af[kt], bf, acc[nt], 0, 0, 0);
        }
      }
      // C-layout -> A-layout via LDS: hid[m][unit], swizzled by m
#pragma unroll
      for (int nt = 0; nt < 8; ++nt) {
        int unit = nt * 16 + col;
#pragma unroll
        for (int r = 0; r < 4; ++r) {
          int m = quad * 4 + r;
          float h = acc[nt][r] + b1v[nt];
          h = h > 0.0f ? h : 0.0f;
          myhid[m * 128 + (((unit >> 3) ^ m) << 3) + (unit & 7)] = f2bf(h);
        }
      }

      // ---- stage 2: M = hidden @ W2 + b2 ----
      f32x4 acc2[4];
#pragma unroll
      for (int nt = 0; nt < 4; ++nt) acc2[nt] = (f32x4)0.0f;
#pragma unroll
      for (int kt = 0; kt < 4; ++kt) {
        int kblk = kt * 4 + quad;
        const bf16x8 ah = *(const bf16x8*)&myhid[col * 128 + ((kblk ^ col) << 3)];
#pragma unroll
        for (int nt = 0; nt < 4; ++nt) {
          int n = nt * 16 + col;
          const bf16x8 bf = *(const bf16x8*)&w2t[n * 128 + ((kblk ^ (n & 15)) << 3)];
          acc2[nt] = __builtin_amdgcn_mfma_f32_16x16x32_bf16(ah, bf, acc2[nt], 0, 0, 0);
        }
      }

      // ---- scatter: atomicAdd into out[node] ----
#pragma unroll
      for (int r = 0; r < 4; ++r) {
        int em = quad * 4 + r;                       // edge row in tile
        int node = __shfl(dir == 0 ? ie : je, em, 64);
        float* dst = out + (long)node * 64;
#pragma unroll
        for (int nt = 0; nt < 4; ++nt) {
          atomicAdd(dst + nt * 16 + col, acc2[nt][r] + b2v[nt]);
        }
      }
    } // dir
  } // tiles
}

extern "C" void kernel_launch(void* const* d_in, const int* in_sizes, int n_in,
                              void* d_out, int out_size, void* d_ws, size_t ws_size,
                              hipStream_t stream) {
  const float* nodes = (const float*)d_in[0];
  const int*   edges = (const int*)d_in[1];
  const float* W1    = (const float*)d_in[2];
  const float* b1    = (const float*)d_in[3];
  const float* W2    = (const float*)d_in[4];
  const float* b2    = (const float*)d_in[5];
  float* out = (float*)d_out;

  // out = nodes  (100000*64 floats = 1,600,000 float4s)
  init_out<<<6250, 256, 0, stream>>>(nodes, out);
  // 1,600,000 edges = 3125 blocks * (4 waves * 8 tiles * 16 edges)
  edge_mlp<<<3125, 256, 0, stream>>>(nodes, edges, W1, b1, W2, b2, out);
}